// Round 1
// baseline (173.020 us; speedup 1.0000x reference)
//
#include <hip/hip_runtime.h>

#define HGT 128
#define WID 128
#define HW  (HGT*WID)      // 16384
#define CIN 64

// ---------------------------------------------------------------------------
// Pass 1: per-pixel 1x1 convs f1/f2 (16 ch each), |f2|^2, bilinear upsample of
// `out` (align_corners). Weights are read with uniform addresses -> scalar
// cache (s_load), no LDS. Outputs pixel-major for float4 reads in pass 2.
//   f1o: [N*HW][16]   f2o: [N*HW][16]   rec: [N*HW] float4 {o0,o1,f2sq,0}
// ---------------------------------------------------------------------------
__global__ __launch_bounds__(256) void pass1_kernel(
    const float* __restrict__ delta, const float* __restrict__ outlo,
    const float* __restrict__ w1, const float* __restrict__ b1,
    const float* __restrict__ w2, const float* __restrict__ b2,
    float* __restrict__ f1o, float* __restrict__ f2o, float4* __restrict__ rec)
{
    const int g = blockIdx.x * 256 + threadIdx.x;   // 0..65535
    const int n = g >> 14;
    const int p = g & (HW - 1);

    float f1a[16], f2a[16];
#pragma unroll
    for (int o = 0; o < 16; ++o) { f1a[o] = b1[o]; f2a[o] = b2[o]; }

    const float* dbase = delta + n * CIN * HW + p;
#pragma unroll 8
    for (int c = 0; c < CIN; ++c) {
        const float d = dbase[c * HW];
#pragma unroll
        for (int o = 0; o < 16; ++o) {
            f1a[o] = fmaf(w1[o * CIN + c], d, f1a[o]);   // uniform -> s_load
            f2a[o] = fmaf(w2[o * CIN + c], d, f2a[o]);
        }
    }

    float f2sq = 0.f;
#pragma unroll
    for (int o = 0; o < 16; ++o) f2sq = fmaf(f2a[o], f2a[o], f2sq);

    float4* f1v = (float4*)(f1o + (size_t)g * 16);
    float4* f2v = (float4*)(f2o + (size_t)g * 16);
#pragma unroll
    for (int k = 0; k < 4; ++k) {
        f1v[k] = make_float4(f1a[4*k], f1a[4*k+1], f1a[4*k+2], f1a[4*k+3]);
        f2v[k] = make_float4(f2a[4*k], f2a[4*k+1], f2a[4*k+2], f2a[4*k+3]);
    }

    // bilinear align_corners upsample of out [N,2,64,64] at (y,x)
    const int y = p >> 7, x = p & 127;
    const float ys = (float)(y * 63) / 127.0f;      // exact 63.0 at y=127
    const float xs = (float)(x * 63) / 127.0f;
    const int iy0 = (int)ys, ix0 = (int)xs;
    const float fy = ys - (float)iy0, fx = xs - (float)ix0;
    const int iy1 = min(iy0 + 1, 63), ix1 = min(ix0 + 1, 63);
    const float* ob = outlo + n * 2 * 4096;
    float o01[2];
#pragma unroll
    for (int cc = 0; cc < 2; ++cc) {
        const float* oc = ob + cc * 4096;
        const float v00 = oc[iy0*64+ix0], v01 = oc[iy0*64+ix1];
        const float v10 = oc[iy1*64+ix0], v11 = oc[iy1*64+ix1];
        const float top = v00 + fx * (v01 - v00);
        const float bot = v10 + fx * (v11 - v10);
        o01[cc] = top + fy * (bot - top);
    }
    rec[g] = make_float4(o01[0], o01[1], f2sq, 0.f);
}

// ---------------------------------------------------------------------------
// Pass 2: per-pixel 81-tap correlation + softmax + aggregation.
// logit = gd*(2*f1.f2 - |f1|^2 - |f2|^2) + gs*ab.  No max-subtraction needed:
// delta_logits <= 0 and gs*ab is O(5), exp cannot overflow.
// ---------------------------------------------------------------------------
__global__ __launch_bounds__(256) void pass2_kernel(
    const float* __restrict__ f1o, const float* __restrict__ f2o,
    const float4* __restrict__ rec, const float* __restrict__ ab,
    const float* __restrict__ gdp, const float* __restrict__ gsp,
    float* __restrict__ outp)
{
    const float gd = gdp[0], gs = gsp[0];
    const int x = blockIdx.x * 64 + threadIdx.x;    // 0..127
    const int y = blockIdx.y * 4 + threadIdx.y;     // 0..127
    const int n = blockIdx.z;
    const int p = y * WID + x;
    const int g = n * HW + p;

    float f1r[16];
    {
        const float4* f1v = (const float4*)(f1o + (size_t)g * 16);
#pragma unroll
        for (int k = 0; k < 4; ++k) {
            float4 t = f1v[k];
            f1r[4*k] = t.x; f1r[4*k+1] = t.y; f1r[4*k+2] = t.z; f1r[4*k+3] = t.w;
        }
    }
    float f1sq = 0.f;
#pragma unroll
    for (int o = 0; o < 16; ++o) f1sq = fmaf(f1r[o], f1r[o], f1sq);
    const float c0 = -gd * f1sq;

    int nyv[9], nxv[9];
#pragma unroll
    for (int i = 0; i < 9; ++i) {
        int vy = y + i - 4; nyv[i] = vy < 0 ? -vy : (vy > 127 ? 254 - vy : vy);
        int vx = x + i - 4; nxv[i] = vx < 0 ? -vx : (vx > 127 ? 254 - vx : vx);
    }

    float s = 0.f, a0 = 0.f, a1 = 0.f;
    const float* abbase = ab + n * 81 * HW + p;

    for (int i = 0; i < 9; ++i) {
        const float4* frow = (const float4*)f2o + (n * HW + nyv[i] * WID) * 4;
        const float4* rrow = rec + (n * HW + nyv[i] * WID);
        const float*  abr  = abbase + i * 9 * HW;
#pragma unroll
        for (int j = 0; j < 9; ++j) {
            const int q = nxv[j];
            const float4 A = frow[q*4+0], B = frow[q*4+1];
            const float4 C = frow[q*4+2], D = frow[q*4+3];
            float d0 = f1r[0]*A.x, d1 = f1r[1]*A.y, d2 = f1r[2]*A.z, d3 = f1r[3]*A.w;
            d0 = fmaf(f1r[ 4], B.x, d0); d1 = fmaf(f1r[ 5], B.y, d1);
            d2 = fmaf(f1r[ 6], B.z, d2); d3 = fmaf(f1r[ 7], B.w, d3);
            d0 = fmaf(f1r[ 8], C.x, d0); d1 = fmaf(f1r[ 9], C.y, d1);
            d2 = fmaf(f1r[10], C.z, d2); d3 = fmaf(f1r[11], C.w, d3);
            d0 = fmaf(f1r[12], D.x, d0); d1 = fmaf(f1r[13], D.y, d1);
            d2 = fmaf(f1r[14], D.z, d2); d3 = fmaf(f1r[15], D.w, d3);
            const float dot = (d0 + d1) + (d2 + d3);
            const float4 R = rrow[q];
            const float e = fmaf(gd, fmaf(2.f, dot, -R.z), fmaf(gs, abr[j*HW], c0));
            const float w = __expf(e);
            s += w;
            a0 = fmaf(w, R.x, a0);
            a1 = fmaf(w, R.y, a1);
        }
    }
    const float inv = 1.0f / s;
    outp[(n * 2 + 0) * HW + p] = a0 * inv;
    outp[(n * 2 + 1) * HW + p] = a1 * inv;
}

extern "C" void kernel_launch(void* const* d_in, const int* in_sizes, int n_in,
                              void* d_out, int out_size, void* d_ws, size_t ws_size,
                              hipStream_t stream) {
    const float* delta = (const float*)d_in[0];   // [4,64,128,128]
    const float* outlo = (const float*)d_in[1];   // [4,2,64,64]
    const float* ab    = (const float*)d_in[2];   // [4,81,16384]
    const float* w1    = (const float*)d_in[3];   // [16,64]
    const float* b1    = (const float*)d_in[4];   // [16]
    const float* w2    = (const float*)d_in[5];   // [16,64]
    const float* b2    = (const float*)d_in[6];   // [16]
    const float* gd    = (const float*)d_in[7];   // scalar
    const float* gs    = (const float*)d_in[8];   // scalar
    float* outp = (float*)d_out;                  // [4,2,128,128]

    float*  f1o = (float*)d_ws;                   // 4 MiB
    float*  f2o = f1o + (size_t)4 * HW * 16;      // 4 MiB
    float4* rec = (float4*)(f2o + (size_t)4 * HW * 16); // 1 MiB

    pass1_kernel<<<dim3(256), dim3(256), 0, stream>>>(delta, outlo, w1, b1, w2, b2,
                                                      f1o, f2o, rec);
    pass2_kernel<<<dim3(2, 32, 4), dim3(64, 4, 1), 0, stream>>>(f1o, f2o, rec, ab,
                                                                gd, gs, outp);
}

// Round 2
// 110.556 us; speedup vs baseline: 1.5650x; 1.5650x over previous
//
#include <hip/hip_runtime.h>

#define HGT 128
#define WID 128
#define HW  (HGT*WID)        // 16384
#define CIN 64
#define NPIX (4*HW)          // 65536 pixels total
#define TS 16                // pass2 tile side
#define HS 24                // halo side (TS + 2*4)
#define HPX (HS*HS)          // 576

// ---------------------------------------------------------------------------
// Pass 1: per-pixel 1x1 convs f1/f2 (16 ch each), |f2|^2, bilinear upsample.
// Weights staged in LDS transposed [c][32] and read with wave-uniform
// addresses -> LDS broadcast (no bank BW, no scalar-load latency chains).
// Outputs plane-major: f1p/f2p are float4[4][NPIX]; rec is float4[NPIX].
// ---------------------------------------------------------------------------
__global__ __launch_bounds__(256) void pass1_kernel(
    const float* __restrict__ delta, const float* __restrict__ outlo,
    const float* __restrict__ w1, const float* __restrict__ b1,
    const float* __restrict__ w2, const float* __restrict__ b2,
    float4* __restrict__ f1p, float4* __restrict__ f2p, float4* __restrict__ rec)
{
    __shared__ float wlds[64][32];   // [c][o]; o<16 -> w1[o], o>=16 -> w2[o-16]
    {
        const int t = threadIdx.x;
#pragma unroll
        for (int s = 0; s < 8; ++s) {
            const int idx = t + s * 256;          // 0..2047
            const int c = idx >> 5, o = idx & 31;
            wlds[c][o] = (o < 16) ? w1[o * 64 + c] : w2[(o - 16) * 64 + c];
        }
    }
    __syncthreads();

    const int g = blockIdx.x * 256 + threadIdx.x;   // 0..65535
    const int n = g >> 14;
    const int p = g & (HW - 1);

    float f1a[16], f2a[16];
#pragma unroll
    for (int o = 0; o < 16; ++o) { f1a[o] = b1[o]; f2a[o] = b2[o]; }

    const float* dbase = delta + n * CIN * HW + p;
#pragma unroll 4
    for (int c = 0; c < CIN; ++c) {
        const float d = dbase[c * HW];
        const float4* wr = (const float4*)(&wlds[c][0]);  // uniform -> broadcast
#pragma unroll
        for (int k = 0; k < 4; ++k) {
            const float4 wv = wr[k];
            f1a[4*k+0] = fmaf(wv.x, d, f1a[4*k+0]);
            f1a[4*k+1] = fmaf(wv.y, d, f1a[4*k+1]);
            f1a[4*k+2] = fmaf(wv.z, d, f1a[4*k+2]);
            f1a[4*k+3] = fmaf(wv.w, d, f1a[4*k+3]);
        }
#pragma unroll
        for (int k = 0; k < 4; ++k) {
            const float4 wv = wr[4 + k];
            f2a[4*k+0] = fmaf(wv.x, d, f2a[4*k+0]);
            f2a[4*k+1] = fmaf(wv.y, d, f2a[4*k+1]);
            f2a[4*k+2] = fmaf(wv.z, d, f2a[4*k+2]);
            f2a[4*k+3] = fmaf(wv.w, d, f2a[4*k+3]);
        }
    }

    float f2sq = 0.f;
#pragma unroll
    for (int o = 0; o < 16; ++o) f2sq = fmaf(f2a[o], f2a[o], f2sq);

#pragma unroll
    for (int k = 0; k < 4; ++k) {
        f1p[k * NPIX + g] = make_float4(f1a[4*k], f1a[4*k+1], f1a[4*k+2], f1a[4*k+3]);
        f2p[k * NPIX + g] = make_float4(f2a[4*k], f2a[4*k+1], f2a[4*k+2], f2a[4*k+3]);
    }

    // bilinear align_corners upsample of out [N,2,64,64] at (y,x)
    const int y = p >> 7, x = p & 127;
    const float ys = (float)(y * 63) / 127.0f;
    const float xs = (float)(x * 63) / 127.0f;
    const int iy0 = (int)ys, ix0 = (int)xs;
    const float fy = ys - (float)iy0, fx = xs - (float)ix0;
    const int iy1 = min(iy0 + 1, 63), ix1 = min(ix0 + 1, 63);
    const float* ob = outlo + n * 2 * 4096;
    float o01[2];
#pragma unroll
    for (int cc = 0; cc < 2; ++cc) {
        const float* oc = ob + cc * 4096;
        const float v00 = oc[iy0*64+ix0], v01 = oc[iy0*64+ix1];
        const float v10 = oc[iy1*64+ix0], v11 = oc[iy1*64+ix1];
        const float top = v00 + fx * (v01 - v00);
        const float bot = v10 + fx * (v11 - v10);
        o01[cc] = top + fy * (bot - top);
    }
    rec[g] = make_float4(o01[0], o01[1], f2sq, 0.f);
}

// ---------------------------------------------------------------------------
// Pass 2: 16x16 pixel tile per block. Halo (24x24) of f2 (4 planes) + rec
// (1 plane) staged in LDS as float4[5][576] (plane-major: consecutive lanes
// read consecutive 16B -> conflict-free). 81 taps from LDS, ab streamed.
// ---------------------------------------------------------------------------
__global__ __launch_bounds__(256) void pass2_kernel(
    const float4* __restrict__ f1p, const float4* __restrict__ f2p,
    const float4* __restrict__ rec, const float* __restrict__ ab,
    const float* __restrict__ gdp, const float* __restrict__ gsp,
    float* __restrict__ outp)
{
    __shared__ float4 sf[5][HPX];

    const int t = threadIdx.x;
    const int n = blockIdx.z;
    const int bx = blockIdx.x * TS, by = blockIdx.y * TS;

    // ---- fill halo ----
#pragma unroll
    for (int s = 0; s < 3; ++s) {
        const int px = t + s * 256;
        if (px < HPX) {
            const int hy = px / 24, hx = px - hy * 24;
            int gy = by - 4 + hy; gy = gy < 0 ? -gy : (gy > 127 ? 254 - gy : gy);
            int gx = bx - 4 + hx; gx = gx < 0 ? -gx : (gx > 127 ? 254 - gx : gx);
            const int gp = n * HW + gy * 128 + gx;
            sf[0][px] = f2p[0 * NPIX + gp];
            sf[1][px] = f2p[1 * NPIX + gp];
            sf[2][px] = f2p[2 * NPIX + gp];
            sf[3][px] = f2p[3 * NPIX + gp];
            sf[4][px] = rec[gp];
        }
    }
    __syncthreads();

    const float gd = gdp[0], gs = gsp[0];
    const int tx = t & 15, ty = t >> 4;
    const int p = (by + ty) * 128 + (bx + tx);
    const int g = n * HW + p;

    float f1r[16];
#pragma unroll
    for (int k = 0; k < 4; ++k) {
        const float4 v = f1p[k * NPIX + g];
        f1r[4*k] = v.x; f1r[4*k+1] = v.y; f1r[4*k+2] = v.z; f1r[4*k+3] = v.w;
    }
    float f1sq = 0.f;
#pragma unroll
    for (int o = 0; o < 16; ++o) f1sq = fmaf(f1r[o], f1r[o], f1sq);
    const float c0 = -gd * f1sq;
    const float gd2 = 2.0f * gd;

    float s_ = 0.f, a0 = 0.f, a1 = 0.f;
    const float* abbase = ab + n * 81 * HW + p;

    for (int i = 0; i < 9; ++i) {
        const int hbase = (ty + i) * HS + tx;
        const float* abr = abbase + i * 9 * HW;
#pragma unroll
        for (int j = 0; j < 9; ++j) {
            const int h = hbase + j;
            const float4 A = sf[0][h], B = sf[1][h];
            const float4 C = sf[2][h], D = sf[3][h];
            float d0 = f1r[0]*A.x, d1 = f1r[1]*A.y, d2 = f1r[2]*A.z, d3 = f1r[3]*A.w;
            d0 = fmaf(f1r[ 4], B.x, d0); d1 = fmaf(f1r[ 5], B.y, d1);
            d2 = fmaf(f1r[ 6], B.z, d2); d3 = fmaf(f1r[ 7], B.w, d3);
            d0 = fmaf(f1r[ 8], C.x, d0); d1 = fmaf(f1r[ 9], C.y, d1);
            d2 = fmaf(f1r[10], C.z, d2); d3 = fmaf(f1r[11], C.w, d3);
            d0 = fmaf(f1r[12], D.x, d0); d1 = fmaf(f1r[13], D.y, d1);
            d2 = fmaf(f1r[14], D.z, d2); d3 = fmaf(f1r[15], D.w, d3);
            const float dot = (d0 + d1) + (d2 + d3);
            const float4 R = sf[4][h];
            float e = fmaf(-gd, R.z, fmaf(gd2, dot, c0));
            e = fmaf(gs, abr[j * HW], e);
            const float w = __expf(e);
            s_ += w;
            a0 = fmaf(w, R.x, a0);
            a1 = fmaf(w, R.y, a1);
        }
    }
    const float inv = 1.0f / s_;
    outp[(n * 2 + 0) * HW + p] = a0 * inv;
    outp[(n * 2 + 1) * HW + p] = a1 * inv;
}

extern "C" void kernel_launch(void* const* d_in, const int* in_sizes, int n_in,
                              void* d_out, int out_size, void* d_ws, size_t ws_size,
                              hipStream_t stream) {
    const float* delta = (const float*)d_in[0];   // [4,64,128,128]
    const float* outlo = (const float*)d_in[1];   // [4,2,64,64]
    const float* ab    = (const float*)d_in[2];   // [4,81,16384]
    const float* w1    = (const float*)d_in[3];   // [16,64]
    const float* b1    = (const float*)d_in[4];   // [16]
    const float* w2    = (const float*)d_in[5];   // [16,64]
    const float* b2    = (const float*)d_in[6];   // [16]
    const float* gd    = (const float*)d_in[7];   // scalar
    const float* gs    = (const float*)d_in[8];   // scalar
    float* outp = (float*)d_out;                  // [4,2,128,128]

    float4* f1p = (float4*)d_ws;                  // 4 MiB (4 planes x NPIX)
    float4* f2p = f1p + (size_t)4 * NPIX;         // 4 MiB
    float4* rec = f2p + (size_t)4 * NPIX;         // 1 MiB

    pass1_kernel<<<dim3(256), dim3(256), 0, stream>>>(delta, outlo, w1, b1, w2, b2,
                                                      f1p, f2p, rec);
    pass2_kernel<<<dim3(8, 8, 4), dim3(256), 0, stream>>>(f1p, f2p, rec, ab,
                                                          gd, gs, outp);
}